// Round 1
// 472.971 us; speedup vs baseline: 1.0289x; 1.0289x over previous
//
#include <hip/hip_runtime.h>

// Problem constants (fixed by the reference)
#define KS   5      // kernel size
#define DIL  2      // dilation
#define PAD  4      // (KS/2)*DIL
#define B_   4
#define C_   32
#define P_   8
#define OUTC 24     // DYNAMIC_SIZE
#define H_   512
#define W_   512
#define HW   (H_ * W_)

typedef float2 f2;

// v2: 2 pixels/thread (float2 state -> ~half the VGPRs of the 4px version),
// one full image row per 256-thread block, scalar (b,y) from blockIdx so all
// row offsets live in SGPRs, XCD-aware block swizzle so the 9-row dy-reuse
// window stays inside one XCD's L2.
__global__ __launch_bounds__(256, 3)
void bilateral2(const float* __restrict__ inp,   // (B, C, H, W)
                const float* __restrict__ par,   // (B, P, H, W)
                float* __restrict__ out)         // (B, OUTC, H, W)
{
    // ---- XCD-aware swizzle: 2048 blocks -> 8 chunks of 256 consecutive rows.
    // Dispatcher round-robins blockIdx across 8 XCDs; this remap gives each
    // XCD a contiguous row range so dy-neighbor re-reads hit its own L2.
    const int nwg = gridDim.x;                   // 2048 (divisible by 8 -> bijective)
    const int bid = blockIdx.x;
    const int sb  = (bid & 7) * (nwg >> 3) + (bid >> 3);

    const int b = sb >> 9;                       // 512 rows per batch image
    const int y = sb & (H_ - 1);                 // scalar: whole block shares y
    const int x0 = threadIdx.x << 1;             // 2 px per thread

    const float* __restrict__ parb = par + (size_t)b * P_ * HW;
    const float* __restrict__ inpb = inp + (size_t)b * C_ * HW;
    float* __restrict__ outb       = out + (size_t)b * OUTC * HW;

    // per-dy clamped row offsets + validity — all scalar (SGPR)
    int  rowoff[KS];
    bool rowok[KS];
#pragma unroll
    for (int d = 0; d < KS; ++d) {
        const int yy = y + d * DIL - PAD;
        rowok[d]  = (yy >= 0) & (yy < H_);
        rowoff[d] = min(max(yy, 0), H_ - 1) * W_;
    }

    // 5 aligned float2 chunk bases; tap e == chunk e (x0 even => 8B aligned).
    // Fully-OOB chunks are clamped to a valid address; they only feed taps
    // whose d2 is initialized to BIG below (weight == 0), so values are inert.
    int cbx[KS];
#pragma unroll
    for (int e = 0; e < KS; ++e) {
        const int xx = x0 + e * DIL - PAD;
        cbx[e] = min(max(xx, 0), W_ - 2);
    }

    // ---- d2 init: 0 for valid taps, BIG for invalid taps.
    // __expf(-(BIG + anything_finite_nonneg)) underflows to exactly 0.f,
    // which reproduces the reference's zero-weight masking with no mask regs.
    f2 d2[KS * KS];
#pragma unroll
    for (int d = 0; d < KS; ++d) {
#pragma unroll
        for (int e = 0; e < KS; ++e) {
            const int xb = x0 + e * DIL - PAD;
            const bool ok0 = rowok[d] & (xb + 0 >= 0) & (xb + 0 < W_);
            const bool ok1 = rowok[d] & (xb + 1 >= 0) & (xb + 1 < W_);
            d2[d * KS + e].x = ok0 ? 0.f : 1e5f;
            d2[d * KS + e].y = ok1 ? 0.f : 1e5f;
        }
    }

    // ---- weight phase: accumulate d2 over the 8 guide channels ----
#pragma unroll 2
    for (int p = 0; p < P_; ++p) {
        const float* __restrict__ pp = parb + p * HW;
        const f2 pc = *(const f2*)(pp + y * W_ + x0);   // center params, 2 px
#pragma unroll
        for (int d = 0; d < KS; ++d) {
            const float* __restrict__ rp = pp + rowoff[d];
#pragma unroll
            for (int e = 0; e < KS; ++e) {
                const f2 v = *(const f2*)(rp + cbx[e]);
                const float dx0 = pc.x - v.x;
                const float dx1 = pc.y - v.y;
                d2[d * KS + e].x += dx0 * dx0;
                d2[d * KS + e].y += dx1 * dx1;
            }
        }
    }

    // ---- exp + normalize (masking already folded into d2 init) ----
    f2 w[KS * KS];
    float wsx = 0.f, wsy = 0.f;
#pragma unroll
    for (int t = 0; t < KS * KS; ++t) {
        w[t].x = __expf(-d2[t].x);
        w[t].y = __expf(-d2[t].y);
        wsx += w[t].x;
        wsy += w[t].y;
    }
    const float ivx = 1.f / (wsx + 1e-8f);
    const float ivy = 1.f / (wsy + 1e-8f);
#pragma unroll
    for (int t = 0; t < KS * KS; ++t) { w[t].x *= ivx; w[t].y *= ivy; }

    // ---- channel loop: 25 aligned float2 loads per (c, dy-row set) ----
    const int obase = y * W_ + x0;
#pragma unroll 2
    for (int c = 0; c < OUTC; ++c) {
        const float* __restrict__ ic = inpb + c * HW;
        f2 acc = make_float2(0.f, 0.f);
#pragma unroll
        for (int d = 0; d < KS; ++d) {
            const float* __restrict__ rp = ic + rowoff[d];
#pragma unroll
            for (int e = 0; e < KS; ++e) {
                const f2 v  = *(const f2*)(rp + cbx[e]);
                const f2 ww = w[d * KS + e];
                acc.x += ww.x * v.x;
                acc.y += ww.y * v.y;
            }
        }
        *(f2*)(outb + c * HW + obase) = acc;
    }
}

extern "C" void kernel_launch(void* const* d_in, const int* in_sizes, int n_in,
                              void* d_out, int out_size, void* d_ws, size_t ws_size,
                              hipStream_t stream) {
    const float* inp = (const float*)d_in[0];   // (4,32,512,512) fp32
    const float* par = (const float*)d_in[1];   // (4,8,512,512) fp32
    float* out = (float*)d_out;                 // (4,24,512,512) fp32

    dim3 block(256);
    dim3 grid(B_ * H_);                         // 2048 blocks: one row each
    bilateral2<<<grid, block, 0, stream>>>(inp, par, out);
}